// Round 9
// baseline (215.359 us; speedup 1.0000x reference)
//
#include <hip/hip_runtime.h>
#include <math.h>

#define B_   2
#define N_   2048
#define D_   1024
#define H_   16
#define HD_  64
#define BH_  32
#define M_   4096   // B_*N_

typedef __bf16 bf16x8 __attribute__((ext_vector_type(8)));
typedef float  f32x4  __attribute__((ext_vector_type(4)));

__device__ inline unsigned short f2b(float f) {
    unsigned u = __float_as_uint(f);
    u += 0x7FFFu + ((u >> 16) & 1u);
    return (unsigned short)(u >> 16);
}
// cheap round (1 ulp vs RNE on ties; P has huge margin)
__device__ inline unsigned short f2b_fast(float f) {
    return (unsigned short)((__float_as_uint(f) + 0x8000u) >> 16);
}
// pack 8 fp32 -> 8 bf16 (RNE, same as f2b -> bit-identical to the old cvt_all)
__device__ inline uint4 pk8(float4 a, float4 b) {
    uint4 u;
    u.x = (uint)f2b(a.x) | ((uint)f2b(a.y) << 16);
    u.y = (uint)f2b(a.z) | ((uint)f2b(a.w) << 16);
    u.z = (uint)f2b(b.x) | ((uint)f2b(b.y) << 16);
    u.w = (uint)f2b(b.z) | ((uint)f2b(b.w) << 16);
    return u;
}

// ---------------------------------------------------------------------------
// QKV bf16 MFMA GEMM with INLINE fp32->bf16 conversion (cvt_all fused away).
// C = A @ W^T. X [Mx1024] fp32, W [1024x1024] fp32, both row-major.
// 128x128 tile, 4 waves 2x2, 64x64/wave, BK=32. Register-prefetch staging:
// next tile's fp32 loads (8x float4/thread) issue right after the barrier,
// converted to bf16 at LDS-write time next iteration.
// z=0 (Q): scaled by 0.125*log2e (exp2-domain softmax) -> [BH][N][64]
// z=1 (K): [BH][N][64];  z=2 (V): TRANSPOSED [BH][HD][N] (ushort4 stores).
// Layouts (HW-verified m89/m91/m120): A-frag (m=lane&15, k=quad*8+j),
// B-frag (k=quad*8+j, n=lane&15), C/D col=lane&15, row=quad*4+reg.
// ---------------------------------------------------------------------------
__global__ __launch_bounds__(256)
void gemm_qkv(const float* __restrict__ X,
              const float* __restrict__ W0, const float* __restrict__ W1,
              const float* __restrict__ W2,
              ushort* __restrict__ O0, ushort* __restrict__ O1,
              ushort* __restrict__ O2)
{
    const int z = blockIdx.z;
    const float* W = (z == 0) ? W0 : (z == 1) ? W1 : W2;

    __shared__ alignas(16) ushort As[128][40];
    __shared__ alignas(16) ushort Bs[128][40];

    const int t = threadIdx.x;
    const int lane = t & 63, w = t >> 6;
    const int quad = lane >> 4, l15 = lane & 15;
    const int wm = (w >> 1) * 64, wn = (w & 1) * 64;
    const int tileM = blockIdx.x * 128, tileN = blockIdx.y * 128;

    const int r0 = t >> 2, r1 = 64 + (t >> 2);
    const int cg = (t & 3) * 8;                  // element col offset (fp32 & bf16)
    const float* GA0 = X + (size_t)(tileM + r0) * D_ + cg;
    const float* GA1 = X + (size_t)(tileM + r1) * D_ + cg;
    const float* GB0 = W + (size_t)(tileN + r0) * D_ + cg;
    const float* GB1 = W + (size_t)(tileN + r1) * D_ + cg;

    f32x4 acc[4][4];
#pragma unroll
    for (int mt = 0; mt < 4; ++mt)
#pragma unroll
        for (int nt = 0; nt < 4; ++nt) acc[mt][nt] = (f32x4){0.f, 0.f, 0.f, 0.f};

    float4 a00 = *(const float4*)GA0, a01 = *(const float4*)(GA0 + 4);
    float4 a10 = *(const float4*)GA1, a11 = *(const float4*)(GA1 + 4);
    float4 b00 = *(const float4*)GB0, b01 = *(const float4*)(GB0 + 4);
    float4 b10 = *(const float4*)GB1, b11 = *(const float4*)(GB1 + 4);

    for (int k0 = 0; k0 < D_; k0 += 32) {
        __syncthreads();                 // prev tile's readers done
        *(uint4*)&As[r0][cg] = pk8(a00, a01);
        *(uint4*)&As[r1][cg] = pk8(a10, a11);
        *(uint4*)&Bs[r0][cg] = pk8(b00, b01);
        *(uint4*)&Bs[r1][cg] = pk8(b10, b11);
        __syncthreads();
        if (k0 + 32 < D_) {              // prefetch next tile (used next iter)
            a00 = *(const float4*)(GA0 + k0 + 32); a01 = *(const float4*)(GA0 + k0 + 36);
            a10 = *(const float4*)(GA1 + k0 + 32); a11 = *(const float4*)(GA1 + k0 + 36);
            b00 = *(const float4*)(GB0 + k0 + 32); b01 = *(const float4*)(GB0 + k0 + 36);
            b10 = *(const float4*)(GB1 + k0 + 32); b11 = *(const float4*)(GB1 + k0 + 36);
        }

        bf16x8 af[4], bf[4];
#pragma unroll
        for (int mt = 0; mt < 4; ++mt) af[mt] = *(const bf16x8*)&As[wm + mt * 16 + l15][quad * 8];
#pragma unroll
        for (int nt = 0; nt < 4; ++nt) bf[nt] = *(const bf16x8*)&Bs[wn + nt * 16 + l15][quad * 8];
#pragma unroll
        for (int mt = 0; mt < 4; ++mt)
#pragma unroll
            for (int nt = 0; nt < 4; ++nt)
                acc[mt][nt] = __builtin_amdgcn_mfma_f32_16x16x32_bf16(af[mt], bf[nt], acc[mt][nt], 0, 0, 0);
    }

    ushort* O = (z == 0) ? O0 : (z == 1) ? O1 : O2;
    // Q: fold 1/sqrt(64) AND log2e (exp2-domain softmax) into the scale
    const float scl = (z == 0) ? 0.18033688f : 1.0f;
#pragma unroll
    for (int mt = 0; mt < 4; ++mt)
#pragma unroll
        for (int nt = 0; nt < 4; ++nt) {
            if (z == 2) {
                // V transposed: Vt[bh][dd][n], 4 consecutive n per 8B store
                int rg0 = tileM + wm + mt * 16 + quad * 4;
                int cgc = tileN + wn + nt * 16 + l15;
                int b = rg0 >> 11, n0 = rg0 & (N_ - 1);
                int h = cgc >> 6, dd = cgc & 63;
                ushort4 o4;
                o4.x = f2b(acc[mt][nt][0]); o4.y = f2b(acc[mt][nt][1]);
                o4.z = f2b(acc[mt][nt][2]); o4.w = f2b(acc[mt][nt][3]);
                *(ushort4*)&O[((size_t)((b * H_ + h) * HD_ + dd)) * N_ + n0] = o4;
            } else {
#pragma unroll
                for (int r = 0; r < 4; ++r) {
                    int rg = tileM + wm + mt * 16 + quad * 4 + r;
                    int cgc = tileN + wn + nt * 16 + l15;
                    int b = rg >> 11, n = rg & (N_ - 1);
                    int h = cgc >> 6, dd = cgc & 63;
                    O[(((size_t)(b * H_ + h)) * N_ + n) * HD_ + dd] = f2b(acc[mt][nt][r] * scl);
                }
            }
        }
}

// ---------------------------------------------------------------------------
// Final GEMM: out = AO @ Wo^T + bias, fp32 out [4096x1024].
// AO bf16 (from attn); Wo fp32 converted inline at staging.
// 128x64 tile (512 blocks = 2/CU). 4 waves 2x2, each 64x32.
// ---------------------------------------------------------------------------
__global__ __launch_bounds__(256)
void gemm_fin(const ushort* __restrict__ A, const float* __restrict__ W,
              const float* __restrict__ bias, float* __restrict__ Of)
{
    __shared__ alignas(16) ushort As[128][40];
    __shared__ alignas(16) ushort Bs[64][40];

    const int t = threadIdx.x;
    const int lane = t & 63, w = t >> 6;
    const int quad = lane >> 4, l15 = lane & 15;
    const int wm = (w >> 1) * 64, wn = (w & 1) * 32;
    const int tileM = blockIdx.x * 128, tileN = blockIdx.y * 64;

    const int r0 = t >> 2, r1 = 64 + (t >> 2);
    const int cg = (t & 3) * 8;
    const ushort* GA0 = A + (size_t)(tileM + r0) * D_ + cg;
    const ushort* GA1 = A + (size_t)(tileM + r1) * D_ + cg;
    const float*  GB0 = W + (size_t)(tileN + r0) * D_ + cg;

    f32x4 acc[4][2];
#pragma unroll
    for (int mt = 0; mt < 4; ++mt)
#pragma unroll
        for (int nt = 0; nt < 2; ++nt) acc[mt][nt] = (f32x4){0.f, 0.f, 0.f, 0.f};

    uint4  pa0 = *(const uint4*)GA0, pa1 = *(const uint4*)GA1;
    float4 b00 = *(const float4*)GB0, b01 = *(const float4*)(GB0 + 4);

    for (int k0 = 0; k0 < D_; k0 += 32) {
        __syncthreads();
        *(uint4*)&As[r0][cg] = pa0;
        *(uint4*)&As[r1][cg] = pa1;
        *(uint4*)&Bs[r0 & 63][cg] = pk8(b00, b01);
        __syncthreads();
        if (k0 + 32 < D_) {
            pa0 = *(const uint4*)(GA0 + k0 + 32);
            pa1 = *(const uint4*)(GA1 + k0 + 32);
            b00 = *(const float4*)(GB0 + k0 + 32);
            b01 = *(const float4*)(GB0 + k0 + 36);
        }

        bf16x8 af[4], bf[2];
#pragma unroll
        for (int mt = 0; mt < 4; ++mt) af[mt] = *(const bf16x8*)&As[wm + mt * 16 + l15][quad * 8];
#pragma unroll
        for (int nt = 0; nt < 2; ++nt) bf[nt] = *(const bf16x8*)&Bs[wn + nt * 16 + l15][quad * 8];
#pragma unroll
        for (int mt = 0; mt < 4; ++mt)
#pragma unroll
            for (int nt = 0; nt < 2; ++nt)
                acc[mt][nt] = __builtin_amdgcn_mfma_f32_16x16x32_bf16(af[mt], bf[nt], acc[mt][nt], 0, 0, 0);
    }

#pragma unroll
    for (int mt = 0; mt < 4; ++mt)
#pragma unroll
        for (int nt = 0; nt < 2; ++nt)
#pragma unroll
            for (int r = 0; r < 4; ++r) {
                int rg = tileM + wm + mt * 16 + quad * 4 + r;
                int cgc = tileN + wn + nt * 16 + l15;
                Of[(size_t)rg * D_ + cgc] = acc[mt][nt][r] + bias[cgc];
            }
}

// ---------------------------------------------------------------------------
// MFMA adaptive-temperature causal flash attention.
// R8 lesson: time is set by (serial chain per stage) x (stage count), not by
// TLP (8 vs 16 waves/CU: identical 72us) nor VALU count (exp2 cut VALUBusy
// 41->35%, time flat). So: FEWER, FATTER STAGES.
// Pass 1 now stages 128 keys per barrier-pair using the SAME LDS (KV[128][72]
// = pass-2's Ks+Vt regions, zero extra LDS): stage count 33 -> ~17, 2x MFMA
// ILP per stage. Always stages 128 rows (base+128 <= 2048 by construction);
// the final chunk masks causally and uses only lastTiles n-tiles.
// Pass 2 unchanged (needs K and V resident simultaneously): 64-key stages.
// Grid 1024 (4 blocks/CU), qt = 31-(bid>>5), bh = bid&31 (XCD L2 locality).
// exp2 domain: Q pre-scaled by 0.125*log2e; Z=sum 2^(s2-C2),
// S2=sum (s2-C2)2^(s2-C2), H=ln2*(log2(Z)-S2/Z), w=2^(fma(beta,s2,-beta*C2)).
// ---------------------------------------------------------------------------
__global__ __launch_bounds__(256)
void attn_mfma(const ushort* __restrict__ Q, const ushort* __restrict__ K,
               const ushort* __restrict__ VT, ushort* __restrict__ AO)
{
    const int bid = blockIdx.x;
    const int qt = 31 - (bid >> 5);
    const int bh = bid & 31;
    const size_t kvbase = (size_t)bh * N_ * HD_;

    __shared__ alignas(16) ushort KV[128][72];      // pass1: 128 keys; pass2: K[0..63]+Vt[64..127]
    __shared__ alignas(16) ushort Ps[4][4][296];    // wave-private P, grp-padded

    const int t = threadIdx.x;
    const int lane = t & 63, w = t >> 6;
    const int quad = lane >> 4, l15 = lane & 15;
    const float SH2 = 11.5416913f;     // 8 * log2(e)
    const float LN2 = 0.69314718f;

    const int skey = t >> 3;            // 0..31
    const int skc  = (t & 7) * 8;       // 0..56
    const ushort* KS = K  + kvbase + (size_t)skey * HD_ + skc;   // + key*HD_
    const ushort* VS0 = VT + kvbase + (size_t)skey * N_ + skc;   // + kb*64
    const ushort* VS1 = VS0 + 32 * N_;

    const int qrow = w * 16 + quad * 4;
    const int b = bh >> 4, h = bh & 15;

    // Q fragments (registers all kernel)
    bf16x8 aq0, aq1;
    {
        const size_t qr = kvbase + (size_t)(qt * 64 + w * 16 + l15) * HD_;
        aq0 = *(const bf16x8*)&Q[qr + quad * 8];
        aq1 = *(const bf16x8*)&Q[qr + 32 + quad * 8];
    }

    float ez[4] = {0.f, 0.f, 0.f, 0.f};
    float sz[4] = {0.f, 0.f, 0.f, 0.f};

    // ---------------- pass 1: Z, S2 (128-key stages) ----------------
    const int nfull = qt >> 1;                              // full unmasked 128-chunks
    const int lastTiles = (((qt + 1) * 64) - nfull * 128) >> 4;   // 4 or 8

    uint4 q0 = *(const uint4*)KS;
    uint4 q1 = *(const uint4*)(KS + 32 * HD_);
    uint4 q2 = *(const uint4*)(KS + 64 * HD_);
    uint4 q3 = *(const uint4*)(KS + 96 * HD_);

    for (int c = 0; c <= nfull; ++c) {
        __syncthreads();
        *(uint4*)&KV[skey][skc]      = q0;
        *(uint4*)&KV[32 + skey][skc] = q1;
        *(uint4*)&KV[64 + skey][skc] = q2;
        *(uint4*)&KV[96 + skey][skc] = q3;
        __syncthreads();
        if (c < nfull) {
            const ushort* nb = KS + (size_t)(c + 1) * (128 * HD_);
            q0 = *(const uint4*)nb;
            q1 = *(const uint4*)(nb + 32 * HD_);
            q2 = *(const uint4*)(nb + 64 * HD_);
            q3 = *(const uint4*)(nb + 96 * HD_);
        }
        if (c < nfull) {                 // 8 tiles, no masks
#pragma unroll
            for (int nt = 0; nt < 8; ++nt) {
                f32x4 sv = (f32x4){0.f, 0.f, 0.f, 0.f};
                sv = __builtin_amdgcn_mfma_f32_16x16x32_bf16(aq0, *(const bf16x8*)&KV[nt * 16 + l15][quad * 8], sv, 0, 0, 0);
                sv = __builtin_amdgcn_mfma_f32_16x16x32_bf16(aq1, *(const bf16x8*)&KV[nt * 16 + l15][32 + quad * 8], sv, 0, 0, 0);
#pragma unroll
                for (int r = 0; r < 4; ++r) {
                    float sh = sv[r] - SH2;
                    float e = __builtin_amdgcn_exp2f(sh);
                    ez[r] += e;
                    sz[r] = fmaf(e, sh, sz[r]);
                }
            }
        } else {                         // final chunk: causal mask, lastTiles tiles
            const int kbase = c * 128;
            const int qglob = qt * 64 + qrow;
            for (int nt = 0; nt < lastTiles; ++nt) {
                f32x4 sv = (f32x4){0.f, 0.f, 0.f, 0.f};
                sv = __builtin_amdgcn_mfma_f32_16x16x32_bf16(aq0, *(const bf16x8*)&KV[nt * 16 + l15][quad * 8], sv, 0, 0, 0);
                sv = __builtin_amdgcn_mfma_f32_16x16x32_bf16(aq1, *(const bf16x8*)&KV[nt * 16 + l15][32 + quad * 8], sv, 0, 0, 0);
                const int kcol = kbase + nt * 16 + l15;
#pragma unroll
                for (int r = 0; r < 4; ++r) {
                    float sh = sv[r] - SH2;
                    float e = (kcol <= qglob + r) ? __builtin_amdgcn_exp2f(sh) : 0.f;
                    ez[r] += e;
                    sz[r] = fmaf(e, sh, sz[r]);
                }
            }
        }
    }
    // hoisted 16-lane butterfly reduce
#pragma unroll
    for (int r = 0; r < 4; ++r) {
#pragma unroll
        for (int off = 1; off < 16; off <<= 1) {
            ez[r] += __shfl_xor(ez[r], off);
            sz[r] += __shfl_xor(sz[r], off);
        }
    }

    // ---------------- entropy -> beta ----------------
    float nbs[4], bl[4];   // w = exp2(fma(beta, s2, -beta*SH2))
#pragma unroll
    for (int r = 0; r < 4; ++r) {
        float Z = ez[r];
        float Hh = LN2 * (__builtin_amdgcn_logf(Z) - sz[r] / Z);
        float bb = 1.f;
        if (Hh > 0.5f) {
            float e2 = Hh * Hh;
            float pp = -0.037f * e2 * e2 + 0.481f * e2 * Hh - 2.3f * e2 + 4.917f * Hh - 1.791f;
            bb = fmaxf(pp, 1.f);
        }
        bl[r] = bb;
        nbs[r] = -bb * SH2;
    }

    // ---------------- pass 2: O, Z' (64-key stages, K + Vt resident) --------
    f32x4 ov[4];
#pragma unroll
    for (int nt = 0; nt < 4; ++nt) ov[nt] = (f32x4){0.f, 0.f, 0.f, 0.f};
    float zp[4] = {0.f, 0.f, 0.f, 0.f};

    uint4 pk0 = *(const uint4*)KS;
    uint4 pk1 = *(const uint4*)(KS + 32 * HD_);
    uint4 pv0 = *(const uint4*)VS0;
    uint4 pv1 = *(const uint4*)VS1;
    for (int kb = 0; kb <= qt; ++kb) {
        __syncthreads();
        *(uint4*)&KV[skey][skc]      = pk0;      // K rows 0..63
        *(uint4*)&KV[32 + skey][skc] = pk1;
        *(uint4*)&KV[64 + skey][skc] = pv0;      // Vt rows (hd) 0..63
        *(uint4*)&KV[96 + skey][skc] = pv1;
        __syncthreads();
        if (kb < qt) {
            const ushort* nk = KS + (size_t)(kb + 1) * (64 * HD_);
            pk0 = *(const uint4*)nk;
            pk1 = *(const uint4*)(nk + 32 * HD_);
            pv0 = *(const uint4*)(VS0 + (kb + 1) * 64);
            pv1 = *(const uint4*)(VS1 + (kb + 1) * 64);
        }
        const bool diag = (kb == qt);

        float wv[4][4];
#pragma unroll
        for (int nt = 0; nt < 4; ++nt) {
            f32x4 sv = (f32x4){0.f, 0.f, 0.f, 0.f};
            sv = __builtin_amdgcn_mfma_f32_16x16x32_bf16(aq0, *(const bf16x8*)&KV[nt * 16 + l15][quad * 8], sv, 0, 0, 0);
            sv = __builtin_amdgcn_mfma_f32_16x16x32_bf16(aq1, *(const bf16x8*)&KV[nt * 16 + l15][32 + quad * 8], sv, 0, 0, 0);
            const int kcol = nt * 16 + l15;
#pragma unroll
            for (int r = 0; r < 4; ++r) {
                float e = __builtin_amdgcn_exp2f(fmaf(bl[r], sv[r], nbs[r]));
                wv[nt][r] = (!diag || (kcol <= qrow + r)) ? e : 0.f;
            }
        }
        // P -> wave-private LDS (C-layout write, A-layout read; same-wave)
#pragma unroll
        for (int nt = 0; nt < 4; ++nt)
#pragma unroll
            for (int r = 0; r < 4; ++r)
                Ps[w][quad][r * 72 + nt * 16 + l15] = f2b_fast(wv[nt][r]);
#pragma unroll
        for (int r = 0; r < 4; ++r)
            zp[r] += (wv[0][r] + wv[1][r]) + (wv[2][r] + wv[3][r]);

        bf16x8 pa0 = *(const bf16x8*)&Ps[w][l15 >> 2][(l15 & 3) * 72 + quad * 8];
        bf16x8 pa1 = *(const bf16x8*)&Ps[w][l15 >> 2][(l15 & 3) * 72 + 32 + quad * 8];
#pragma unroll
        for (int nt = 0; nt < 4; ++nt) {
            ov[nt] = __builtin_amdgcn_mfma_f32_16x16x32_bf16(pa0, *(const bf16x8*)&KV[64 + nt * 16 + l15][quad * 8], ov[nt], 0, 0, 0);
            ov[nt] = __builtin_amdgcn_mfma_f32_16x16x32_bf16(pa1, *(const bf16x8*)&KV[64 + nt * 16 + l15][32 + quad * 8], ov[nt], 0, 0, 0);
        }
    }
    // hoisted Z' butterfly
#pragma unroll
    for (int r = 0; r < 4; ++r)
#pragma unroll
        for (int off = 1; off < 16; off <<= 1) zp[r] += __shfl_xor(zp[r], off);

    // ---------------- write AO [B, N, D] bf16 ----------------
#pragma unroll
    for (int r = 0; r < 4; ++r) {
        int qg = qt * 64 + w * 16 + quad * 4 + r;
        float inv = 1.f / zp[r];
        size_t rowoff = ((size_t)(b * N_ + qg)) * D_ + h * HD_;
#pragma unroll
        for (int nt = 0; nt < 4; ++nt)
            AO[rowoff + nt * 16 + l15] = f2b(ov[nt][r] * inv);
    }
}

// ---------------------------------------------------------------------------
extern "C" void kernel_launch(void* const* d_in, const int* in_sizes, int n_in,
                              void* d_out, int out_size, void* d_ws, size_t ws_size,
                              hipStream_t stream)
{
    const float* x  = (const float*)d_in[0];
    const float* Wq = (const float*)d_in[1];
    const float* Wk = (const float*)d_in[2];
    const float* Wv = (const float*)d_in[3];
    const float* Wo = (const float*)d_in[4];
    const float* bo = (const float*)d_in[5];
    float* out = (float*)d_out;

    ushort* ws  = (ushort*)d_ws;
    ushort* Qb  = ws;                       // [32][2048][64]
    ushort* Kb  = ws + 4194304;             // [32][2048][64]
    ushort* Vtb = ws + 8388608;             // [32][64][2048]  (transposed V)
    ushort* aob = ws + 12582912;            // 4096*1024

    gemm_qkv<<<dim3(32, 8, 3), 256, 0, stream>>>(
        x, Wq, Wk, Wv, Qb, Kb, Vtb);

    attn_mfma<<<dim3(1024), 256, 0, stream>>>(Qb, Kb, Vtb, aob);

    gemm_fin<<<dim3(32, 16), 256, 0, stream>>>(aob, Wo, bo, out);
}

// Round 10
// 210.108 us; speedup vs baseline: 1.0250x; 1.0250x over previous
//
#include <hip/hip_runtime.h>
#include <math.h>

#define B_   2
#define N_   2048
#define D_   1024
#define H_   16
#define HD_  64
#define BH_  32
#define M_   4096   // B_*N_

typedef __bf16 bf16x8 __attribute__((ext_vector_type(8)));
typedef float  f32x4  __attribute__((ext_vector_type(4)));

__device__ inline unsigned short f2b(float f) {
    unsigned u = __float_as_uint(f);
    u += 0x7FFFu + ((u >> 16) & 1u);
    return (unsigned short)(u >> 16);
}
// cheap round (1 ulp vs RNE on ties; P has huge margin)
__device__ inline unsigned short f2b_fast(float f) {
    return (unsigned short)((__float_as_uint(f) + 0x8000u) >> 16);
}
// pack 8 fp32 -> 8 bf16 (RNE, bit-identical to f2b path)
__device__ inline uint4 pk8(float4 a, float4 b) {
    uint4 u;
    u.x = (uint)f2b(a.x) | ((uint)f2b(a.y) << 16);
    u.y = (uint)f2b(a.z) | ((uint)f2b(a.w) << 16);
    u.z = (uint)f2b(b.x) | ((uint)f2b(b.y) << 16);
    u.w = (uint)f2b(b.z) | ((uint)f2b(b.w) << 16);
    return u;
}

// ---------------------------------------------------------------------------
// Convert x (4096x1024) + Wq/Wk/Wv (1024x1024 each) fp32 -> bf16:
// [xb | wqb | wkb | wvb].  Wo is NOT converted (gemm_fin reads it fp32 —
// only 1 pk8/thread/iter there, off the critical path).
// R9 lesson: converting per tile-touch inside gemm_qkv's K-loop put ~2.5x
// the MFMA cycles of VALU on the critical path (VALUBusy 28% vs MfmaUtil
// 13%). Convert once per byte here instead: 42 MB traffic ~= 7us.
// ---------------------------------------------------------------------------
__global__ __launch_bounds__(256)
void cvt_xw(const float* __restrict__ x,  const float* __restrict__ wq,
            const float* __restrict__ wk, const float* __restrict__ wv,
            ushort* __restrict__ dst)
{
    int i = blockIdx.x * 256 + threadIdx.x;      // float4 index
    if (i >= 1835008) return;                    // (4096*1024 + 3*1024*1024)/4
    int fi = i * 4;
    const float* s; int off;
    if (fi < 4194304) { s = x; off = fi; }
    else {
        int r = fi - 4194304;
        int wsel = r >> 20;                      // each W = 2^20 elements
        off = r & 1048575;
        s = (wsel == 0) ? wq : (wsel == 1) ? wk : wv;
    }
    float4 f = *(const float4*)(s + off);
    ushort4 o;
    o.x = f2b(f.x); o.y = f2b(f.y); o.z = f2b(f.z); o.w = f2b(f.w);
    *(ushort4*)(dst + fi) = o;
}

// ---------------------------------------------------------------------------
// QKV bf16 MFMA GEMM (R7-verified form): C = A @ W^T. A [Mx1024] bf16,
// W [1024x1024] bf16, both row-major. 128x128 tile, 4 waves 2x2, 64x64/wave,
// BK=32. Register-prefetch staging; LDS padded [128][40].
// z=0 (Q): scaled by 0.125*log2e (exp2-domain softmax) -> [BH][N][64]
// z=1 (K): [BH][N][64];  z=2 (V): TRANSPOSED [BH][HD][N] (ushort4 stores).
// Layouts (HW-verified m89/m91/m120): A-frag (m=lane&15, k=quad*8+j),
// B-frag (k=quad*8+j, n=lane&15), C/D col=lane&15, row=quad*4+reg.
// ---------------------------------------------------------------------------
__global__ __launch_bounds__(256)
void gemm_qkv(const ushort* __restrict__ A,
              const ushort* __restrict__ W0, const ushort* __restrict__ W1,
              const ushort* __restrict__ W2,
              ushort* __restrict__ O0, ushort* __restrict__ O1,
              ushort* __restrict__ O2)
{
    const int z = blockIdx.z;
    const ushort* W = (z == 0) ? W0 : (z == 1) ? W1 : W2;

    __shared__ alignas(16) ushort As[128][40];
    __shared__ alignas(16) ushort Bs[128][40];

    const int t = threadIdx.x;
    const int lane = t & 63, w = t >> 6;
    const int quad = lane >> 4, l15 = lane & 15;
    const int wm = (w >> 1) * 64, wn = (w & 1) * 64;
    const int tileM = blockIdx.x * 128, tileN = blockIdx.y * 128;

    const int r0 = t >> 2, r1 = 64 + (t >> 2);
    const int cg = (t & 3) * 8;
    const ushort* GA0 = A + (size_t)(tileM + r0) * D_ + cg;
    const ushort* GA1 = A + (size_t)(tileM + r1) * D_ + cg;
    const ushort* GB0 = W + (size_t)(tileN + r0) * D_ + cg;
    const ushort* GB1 = W + (size_t)(tileN + r1) * D_ + cg;

    f32x4 acc[4][4];
#pragma unroll
    for (int mt = 0; mt < 4; ++mt)
#pragma unroll
        for (int nt = 0; nt < 4; ++nt) acc[mt][nt] = (f32x4){0.f, 0.f, 0.f, 0.f};

    uint4 pa0 = *(const uint4*)GA0, pa1 = *(const uint4*)GA1;
    uint4 pb0 = *(const uint4*)GB0, pb1 = *(const uint4*)GB1;

    for (int k0 = 0; k0 < D_; k0 += 32) {
        __syncthreads();                 // prev tile's readers done
        *(uint4*)&As[r0][cg] = pa0;
        *(uint4*)&As[r1][cg] = pa1;
        *(uint4*)&Bs[r0][cg] = pb0;
        *(uint4*)&Bs[r1][cg] = pb1;
        __syncthreads();
        if (k0 + 32 < D_) {              // prefetch next tile (used next iter)
            pa0 = *(const uint4*)(GA0 + k0 + 32);
            pa1 = *(const uint4*)(GA1 + k0 + 32);
            pb0 = *(const uint4*)(GB0 + k0 + 32);
            pb1 = *(const uint4*)(GB1 + k0 + 32);
        }

        bf16x8 af[4], bf[4];
#pragma unroll
        for (int mt = 0; mt < 4; ++mt) af[mt] = *(const bf16x8*)&As[wm + mt * 16 + l15][quad * 8];
#pragma unroll
        for (int nt = 0; nt < 4; ++nt) bf[nt] = *(const bf16x8*)&Bs[wn + nt * 16 + l15][quad * 8];
#pragma unroll
        for (int mt = 0; mt < 4; ++mt)
#pragma unroll
            for (int nt = 0; nt < 4; ++nt)
                acc[mt][nt] = __builtin_amdgcn_mfma_f32_16x16x32_bf16(af[mt], bf[nt], acc[mt][nt], 0, 0, 0);
    }

    ushort* O = (z == 0) ? O0 : (z == 1) ? O1 : O2;
    // Q: fold 1/sqrt(64) AND log2e (exp2-domain softmax) into the scale
    const float scl = (z == 0) ? 0.18033688f : 1.0f;
#pragma unroll
    for (int mt = 0; mt < 4; ++mt)
#pragma unroll
        for (int nt = 0; nt < 4; ++nt) {
            if (z == 2) {
                // V transposed: Vt[bh][dd][n], 4 consecutive n per 8B store
                int rg0 = tileM + wm + mt * 16 + quad * 4;
                int cgc = tileN + wn + nt * 16 + l15;
                int b = rg0 >> 11, n0 = rg0 & (N_ - 1);
                int h = cgc >> 6, dd = cgc & 63;
                ushort4 o4;
                o4.x = f2b(acc[mt][nt][0]); o4.y = f2b(acc[mt][nt][1]);
                o4.z = f2b(acc[mt][nt][2]); o4.w = f2b(acc[mt][nt][3]);
                *(ushort4*)&O[((size_t)((b * H_ + h) * HD_ + dd)) * N_ + n0] = o4;
            } else {
#pragma unroll
                for (int r = 0; r < 4; ++r) {
                    int rg = tileM + wm + mt * 16 + quad * 4 + r;
                    int cgc = tileN + wn + nt * 16 + l15;
                    int b = rg >> 11, n = rg & (N_ - 1);
                    int h = cgc >> 6, dd = cgc & 63;
                    O[(((size_t)(b * H_ + h)) * N_ + n) * HD_ + dd] = f2b(acc[mt][nt][r] * scl);
                }
            }
        }
}

// ---------------------------------------------------------------------------
// Final GEMM: out = AO @ Wo^T + bias, fp32 out [4096x1024].
// AO bf16 (from attn); Wo fp32 converted inline at staging (1 pk8/thread/iter
// only -- cheap, and saves cvt traffic for Wo).
// 128x64 tile (512 blocks = 2/CU). 4 waves 2x2, each 64x32.
// ---------------------------------------------------------------------------
__global__ __launch_bounds__(256)
void gemm_fin(const ushort* __restrict__ A, const float* __restrict__ W,
              const float* __restrict__ bias, float* __restrict__ Of)
{
    __shared__ alignas(16) ushort As[128][40];
    __shared__ alignas(16) ushort Bs[64][40];

    const int t = threadIdx.x;
    const int lane = t & 63, w = t >> 6;
    const int quad = lane >> 4, l15 = lane & 15;
    const int wm = (w >> 1) * 64, wn = (w & 1) * 32;
    const int tileM = blockIdx.x * 128, tileN = blockIdx.y * 64;

    const int r0 = t >> 2, r1 = 64 + (t >> 2);
    const int cg = (t & 3) * 8;
    const ushort* GA0 = A + (size_t)(tileM + r0) * D_ + cg;
    const ushort* GA1 = A + (size_t)(tileM + r1) * D_ + cg;
    const float*  GB0 = W + (size_t)(tileN + r0) * D_ + cg;

    f32x4 acc[4][2];
#pragma unroll
    for (int mt = 0; mt < 4; ++mt)
#pragma unroll
        for (int nt = 0; nt < 2; ++nt) acc[mt][nt] = (f32x4){0.f, 0.f, 0.f, 0.f};

    uint4  pa0 = *(const uint4*)GA0, pa1 = *(const uint4*)GA1;
    float4 b00 = *(const float4*)GB0, b01 = *(const float4*)(GB0 + 4);

    for (int k0 = 0; k0 < D_; k0 += 32) {
        __syncthreads();
        *(uint4*)&As[r0][cg] = pa0;
        *(uint4*)&As[r1][cg] = pa1;
        *(uint4*)&Bs[r0 & 63][cg] = pk8(b00, b01);
        __syncthreads();
        if (k0 + 32 < D_) {
            pa0 = *(const uint4*)(GA0 + k0 + 32);
            pa1 = *(const uint4*)(GA1 + k0 + 32);
            b00 = *(const float4*)(GB0 + k0 + 32);
            b01 = *(const float4*)(GB0 + k0 + 36);
        }

        bf16x8 af[4], bf[2];
#pragma unroll
        for (int mt = 0; mt < 4; ++mt) af[mt] = *(const bf16x8*)&As[wm + mt * 16 + l15][quad * 8];
#pragma unroll
        for (int nt = 0; nt < 2; ++nt) bf[nt] = *(const bf16x8*)&Bs[wn + nt * 16 + l15][quad * 8];
#pragma unroll
        for (int mt = 0; mt < 4; ++mt)
#pragma unroll
            for (int nt = 0; nt < 2; ++nt)
                acc[mt][nt] = __builtin_amdgcn_mfma_f32_16x16x32_bf16(af[mt], bf[nt], acc[mt][nt], 0, 0, 0);
    }

#pragma unroll
    for (int mt = 0; mt < 4; ++mt)
#pragma unroll
        for (int nt = 0; nt < 2; ++nt)
#pragma unroll
            for (int r = 0; r < 4; ++r) {
                int rg = tileM + wm + mt * 16 + quad * 4 + r;
                int cgc = tileN + wn + nt * 16 + l15;
                Of[(size_t)rg * D_ + cgc] = acc[mt][nt][r] + bias[cgc];
            }
}

// ---------------------------------------------------------------------------
// MFMA adaptive-temperature causal flash attention (R7-verified structure:
// 64-key stages, grid 1024 = 4 blocks/CU, register-prefetch staging) with
// R8's exp2-domain math (verified VALU reduction, time-neutral, correct).
// qt = 31-(bid>>5), bh = bid&31 (XCD ~ bh%8 K/V L2 locality).
// Q/K bf16 [BH][N][64]; V pre-transposed [BH][64][N]; Q pre-scaled
// 0.125*log2e so scores s2 are in log2 domain:
//   Z = sum 2^(s2-C2), S2 = sum (s2-C2)2^(s2-C2), C2 = 8*log2e
//   H = ln2*(log2(Z) - S2/Z);  w = exp2(fma(beta, s2, -beta*C2))
// Pass 2: O += w*V via MFMA (P through wave-private LDS), Z' += w; O/Z'.
// ---------------------------------------------------------------------------
__global__ __launch_bounds__(256)
void attn_mfma(const ushort* __restrict__ Q, const ushort* __restrict__ K,
               const ushort* __restrict__ VT, ushort* __restrict__ AO)
{
    const int bid = blockIdx.x;
    const int qt = 31 - (bid >> 5);
    const int bh = bid & 31;
    const size_t kvbase = (size_t)bh * N_ * HD_;

    __shared__ alignas(16) ushort Ks[64][72];       // [key][hd]
    __shared__ alignas(16) ushort Vt[64][72];       // [hd][key]
    __shared__ alignas(16) ushort Ps[4][4][296];    // wave-private P, grp-padded

    const int t = threadIdx.x;
    const int lane = t & 63, w = t >> 6;
    const int quad = lane >> 4, l15 = lane & 15;
    const float SH2 = 11.5416913f;     // 8 * log2(e)
    const float LN2 = 0.69314718f;

    const int skey = t >> 3;            // 0..31
    const int skc  = (t & 7) * 8;       // 0..56
    const ushort* KS0 = K  + kvbase + (size_t)skey * HD_ + skc;        // + kb*64*HD_
    const ushort* KS1 = KS0 + 32 * HD_;
    const ushort* VS0 = VT + kvbase + (size_t)skey * N_ + skc;         // + kb*64
    const ushort* VS1 = VS0 + 32 * N_;

    const int qrow = w * 16 + quad * 4;
    const int b = bh >> 4, h = bh & 15;

    // Q fragments (registers all kernel)
    bf16x8 aq0, aq1;
    {
        const size_t qr = kvbase + (size_t)(qt * 64 + w * 16 + l15) * HD_;
        aq0 = *(const bf16x8*)&Q[qr + quad * 8];
        aq1 = *(const bf16x8*)&Q[qr + 32 + quad * 8];
    }

    float ez[4] = {0.f, 0.f, 0.f, 0.f};
    float sz[4] = {0.f, 0.f, 0.f, 0.f};

    // ---------------- pass 1: Z, S2 ----------------
    uint4 pk0 = *(const uint4*)KS0;
    uint4 pk1 = *(const uint4*)KS1;
    for (int kb = 0; kb <= qt; ++kb) {
        __syncthreads();                       // prev tile's readers done
        *(uint4*)&Ks[skey][skc]      = pk0;    // vmcnt wait hidden by prev compute
        *(uint4*)&Ks[32 + skey][skc] = pk1;
        __syncthreads();
        if (kb < qt) {                         // prefetch kb+1
            pk0 = *(const uint4*)(KS0 + (size_t)(kb + 1) * (64 * HD_));
            pk1 = *(const uint4*)(KS1 + (size_t)(kb + 1) * (64 * HD_));
        }
        if (kb < qt) {                         // off-diagonal: no masks
#pragma unroll
            for (int nt = 0; nt < 4; ++nt) {
                f32x4 sv = (f32x4){0.f, 0.f, 0.f, 0.f};
                sv = __builtin_amdgcn_mfma_f32_16x16x32_bf16(aq0, *(const bf16x8*)&Ks[nt * 16 + l15][quad * 8], sv, 0, 0, 0);
                sv = __builtin_amdgcn_mfma_f32_16x16x32_bf16(aq1, *(const bf16x8*)&Ks[nt * 16 + l15][32 + quad * 8], sv, 0, 0, 0);
#pragma unroll
                for (int r = 0; r < 4; ++r) {
                    float sh = sv[r] - SH2;
                    float e = __builtin_amdgcn_exp2f(sh);
                    ez[r] += e;
                    sz[r] = fmaf(e, sh, sz[r]);
                }
            }
        } else {                               // diagonal: causal mask
#pragma unroll
            for (int nt = 0; nt < 4; ++nt) {
                f32x4 sv = (f32x4){0.f, 0.f, 0.f, 0.f};
                sv = __builtin_amdgcn_mfma_f32_16x16x32_bf16(aq0, *(const bf16x8*)&Ks[nt * 16 + l15][quad * 8], sv, 0, 0, 0);
                sv = __builtin_amdgcn_mfma_f32_16x16x32_bf16(aq1, *(const bf16x8*)&Ks[nt * 16 + l15][32 + quad * 8], sv, 0, 0, 0);
                const int kcol = nt * 16 + l15;
#pragma unroll
                for (int r = 0; r < 4; ++r) {
                    float sh = sv[r] - SH2;
                    float e = (kcol <= qrow + r) ? __builtin_amdgcn_exp2f(sh) : 0.f;
                    ez[r] += e;
                    sz[r] = fmaf(e, sh, sz[r]);
                }
            }
        }
    }
    // hoisted 16-lane butterfly reduce
#pragma unroll
    for (int r = 0; r < 4; ++r) {
#pragma unroll
        for (int off = 1; off < 16; off <<= 1) {
            ez[r] += __shfl_xor(ez[r], off);
            sz[r] += __shfl_xor(sz[r], off);
        }
    }

    // ---------------- entropy -> beta ----------------
    float nbs[4], bl[4];   // w = exp2(fma(beta, s2, -beta*SH2))
#pragma unroll
    for (int r = 0; r < 4; ++r) {
        float Z = ez[r];
        float Hh = LN2 * (__builtin_amdgcn_logf(Z) - sz[r] / Z);
        float bb = 1.f;
        if (Hh > 0.5f) {
            float e2 = Hh * Hh;
            float pp = -0.037f * e2 * e2 + 0.481f * e2 * Hh - 2.3f * e2 + 4.917f * Hh - 1.791f;
            bb = fmaxf(pp, 1.f);
        }
        bl[r] = bb;
        nbs[r] = -bb * SH2;
    }

    // ---------------- pass 2: O, Z' ----------------
    f32x4 ov[4];
#pragma unroll
    for (int nt = 0; nt < 4; ++nt) ov[nt] = (f32x4){0.f, 0.f, 0.f, 0.f};
    float zp[4] = {0.f, 0.f, 0.f, 0.f};

    pk0 = *(const uint4*)KS0;
    pk1 = *(const uint4*)KS1;
    uint4 pv0 = *(const uint4*)VS0;
    uint4 pv1 = *(const uint4*)VS1;
    for (int kb = 0; kb <= qt; ++kb) {
        __syncthreads();
        *(uint4*)&Ks[skey][skc]      = pk0;
        *(uint4*)&Ks[32 + skey][skc] = pk1;
        *(uint4*)&Vt[skey][skc]      = pv0;
        *(uint4*)&Vt[32 + skey][skc] = pv1;
        __syncthreads();
        if (kb < qt) {
            pk0 = *(const uint4*)(KS0 + (size_t)(kb + 1) * (64 * HD_));
            pk1 = *(const uint4*)(KS1 + (size_t)(kb + 1) * (64 * HD_));
            pv0 = *(const uint4*)(VS0 + (kb + 1) * 64);
            pv1 = *(const uint4*)(VS1 + (kb + 1) * 64);
        }
        const bool diag = (kb == qt);

        float wv[4][4];
#pragma unroll
        for (int nt = 0; nt < 4; ++nt) {
            f32x4 sv = (f32x4){0.f, 0.f, 0.f, 0.f};
            sv = __builtin_amdgcn_mfma_f32_16x16x32_bf16(aq0, *(const bf16x8*)&Ks[nt * 16 + l15][quad * 8], sv, 0, 0, 0);
            sv = __builtin_amdgcn_mfma_f32_16x16x32_bf16(aq1, *(const bf16x8*)&Ks[nt * 16 + l15][32 + quad * 8], sv, 0, 0, 0);
            const int kcol = nt * 16 + l15;
#pragma unroll
            for (int r = 0; r < 4; ++r) {
                float e = __builtin_amdgcn_exp2f(fmaf(bl[r], sv[r], nbs[r]));
                wv[nt][r] = (!diag || (kcol <= qrow + r)) ? e : 0.f;
            }
        }
        // P -> wave-private LDS (C-layout write, A-layout read; same-wave)
#pragma unroll
        for (int nt = 0; nt < 4; ++nt)
#pragma unroll
            for (int r = 0; r < 4; ++r)
                Ps[w][quad][r * 72 + nt * 16 + l15] = f2b_fast(wv[nt][r]);
#pragma unroll
        for (int r = 0; r < 4; ++r)
            zp[r] += (wv[0][r] + wv[1][r]) + (wv[2][r] + wv[3][r]);

        bf16x8 pa0 = *(const bf16x8*)&Ps[w][l15 >> 2][(l15 & 3) * 72 + quad * 8];
        bf16x8 pa1 = *(const bf16x8*)&Ps[w][l15 >> 2][(l15 & 3) * 72 + 32 + quad * 8];
#pragma unroll
        for (int nt = 0; nt < 4; ++nt) {
            ov[nt] = __builtin_amdgcn_mfma_f32_16x16x32_bf16(pa0, *(const bf16x8*)&Vt[nt * 16 + l15][quad * 8], ov[nt], 0, 0, 0);
            ov[nt] = __builtin_amdgcn_mfma_f32_16x16x32_bf16(pa1, *(const bf16x8*)&Vt[nt * 16 + l15][32 + quad * 8], ov[nt], 0, 0, 0);
        }
    }
    // hoisted Z' butterfly
#pragma unroll
    for (int r = 0; r < 4; ++r)
#pragma unroll
        for (int off = 1; off < 16; off <<= 1) zp[r] += __shfl_xor(zp[r], off);

    // ---------------- write AO [B, N, D] bf16 ----------------
#pragma unroll
    for (int r = 0; r < 4; ++r) {
        int qg = qt * 64 + w * 16 + quad * 4 + r;
        float inv = 1.f / zp[r];
        size_t rowoff = ((size_t)(b * N_ + qg)) * D_ + h * HD_;
#pragma unroll
        for (int nt = 0; nt < 4; ++nt)
            AO[rowoff + nt * 16 + l15] = f2b(ov[nt][r] * inv);
    }
}

// ---------------------------------------------------------------------------
extern "C" void kernel_launch(void* const* d_in, const int* in_sizes, int n_in,
                              void* d_out, int out_size, void* d_ws, size_t ws_size,
                              hipStream_t stream)
{
    const float* x  = (const float*)d_in[0];
    const float* Wq = (const float*)d_in[1];
    const float* Wk = (const float*)d_in[2];
    const float* Wv = (const float*)d_in[3];
    const float* Wo = (const float*)d_in[4];
    const float* bo = (const float*)d_in[5];
    float* out = (float*)d_out;

    ushort* ws  = (ushort*)d_ws;
    ushort* xb  = ws;                       // 4096*1024
    ushort* wqb = ws + 4194304;             // 1024*1024 each
    ushort* wkb = ws + 5242880;
    ushort* wvb = ws + 6291456;
    ushort* Qb  = ws + 7340032;             // [32][2048][64]
    ushort* Kb  = ws + 11534336;            // [32][2048][64]
    ushort* Vtb = ws + 15728640;            // [32][64][2048]  (transposed V)
    ushort* aob = ws + 19922944;            // 4096*1024

    cvt_xw<<<7168, 256, 0, stream>>>(x, Wq, Wk, Wv, xb);

    gemm_qkv<<<dim3(32, 8, 3), 256, 0, stream>>>(
        xb, wqb, wkb, wvb, Qb, Kb, Vtb);

    attn_mfma<<<dim3(1024), 256, 0, stream>>>(Qb, Kb, Vtb, aob);

    gemm_fin<<<dim3(32, 16), 256, 0, stream>>>(aob, Wo, bo, out);
}

// Round 11
// 202.180 us; speedup vs baseline: 1.0652x; 1.0392x over previous
//
#include <hip/hip_runtime.h>
#include <math.h>

#define B_   2
#define N_   2048
#define D_   1024
#define H_   16
#define HD_  64
#define BH_  32
#define M_   4096   // B_*N_

typedef __bf16 bf16x8 __attribute__((ext_vector_type(8)));
typedef float  f32x4  __attribute__((ext_vector_type(4)));

__device__ inline unsigned short f2b(float f) {
    unsigned u = __float_as_uint(f);
    u += 0x7FFFu + ((u >> 16) & 1u);
    return (unsigned short)(u >> 16);
}
// cheap round (1 ulp vs RNE on ties; P has huge margin)
__device__ inline unsigned short f2b_fast(float f) {
    return (unsigned short)((__float_as_uint(f) + 0x8000u) >> 16);
}

// ---------------------------------------------------------------------------
// Convert x (4096x1024) and Wq/Wk/Wv/Wo (1024x1024 each) fp32 -> bf16 into one
// contiguous ws region: [x | wq | wk | wv | wo].  (R7-verified form. R9/R10
// lesson: inline conversion in any GEMM K-loop puts VALU on the critical path
// and loses more than the cvt kernel costs.)
// ---------------------------------------------------------------------------
__global__ __launch_bounds__(256)
void cvt_all(const float* __restrict__ x,  const float* __restrict__ wq,
             const float* __restrict__ wk, const float* __restrict__ wv,
             const float* __restrict__ wo, ushort* __restrict__ dst)
{
    int i = blockIdx.x * 256 + threadIdx.x;      // float4 index
    if (i >= 2097152) return;                    // (4096*1024 + 4*1024*1024)/4
    int fi = i * 4;
    const float* s; int off;
    if (fi < 4194304) { s = x; off = fi; }
    else {
        int r = fi - 4194304;
        int wsel = r >> 20;                      // each W = 2^20 elements
        off = r & 1048575;
        s = (wsel == 0) ? wq : (wsel == 1) ? wk : (wsel == 2) ? wv : wo;
    }
    float4 f = *(const float4*)(s + off);
    ushort4 o;
    o.x = f2b(f.x); o.y = f2b(f.y); o.z = f2b(f.z); o.w = f2b(f.w);
    *(ushort4*)(dst + fi) = o;
}

// ---------------------------------------------------------------------------
// QKV bf16 MFMA GEMM (R7-verified): C = A @ W^T. 128x128 tile, 4 waves 2x2,
// 64x64/wave, BK=32. Register-prefetch staging; LDS padded [128][40].
// z=0 (Q): scaled by 0.125*log2e (exp2-domain softmax) -> [BH][N][64]
// z=1 (K): [BH][N][64];  z=2 (V): TRANSPOSED [BH][HD][N] (ushort4 stores).
// Layouts (HW-verified m89/m91/m120): A-frag (m=lane&15, k=quad*8+j),
// B-frag (k=quad*8+j, n=lane&15), C/D col=lane&15, row=quad*4+reg.
// ---------------------------------------------------------------------------
__global__ __launch_bounds__(256)
void gemm_qkv(const ushort* __restrict__ A,
              const ushort* __restrict__ W0, const ushort* __restrict__ W1,
              const ushort* __restrict__ W2,
              ushort* __restrict__ O0, ushort* __restrict__ O1,
              ushort* __restrict__ O2)
{
    const int z = blockIdx.z;
    const ushort* W = (z == 0) ? W0 : (z == 1) ? W1 : W2;

    __shared__ alignas(16) ushort As[128][40];
    __shared__ alignas(16) ushort Bs[128][40];

    const int t = threadIdx.x;
    const int lane = t & 63, w = t >> 6;
    const int quad = lane >> 4, l15 = lane & 15;
    const int wm = (w >> 1) * 64, wn = (w & 1) * 64;
    const int tileM = blockIdx.x * 128, tileN = blockIdx.y * 128;

    const int r0 = t >> 2, r1 = 64 + (t >> 2);
    const int cg = (t & 3) * 8;
    const ushort* GA0 = A + (size_t)(tileM + r0) * D_ + cg;
    const ushort* GA1 = A + (size_t)(tileM + r1) * D_ + cg;
    const ushort* GB0 = W + (size_t)(tileN + r0) * D_ + cg;
    const ushort* GB1 = W + (size_t)(tileN + r1) * D_ + cg;

    f32x4 acc[4][4];
#pragma unroll
    for (int mt = 0; mt < 4; ++mt)
#pragma unroll
        for (int nt = 0; nt < 4; ++nt) acc[mt][nt] = (f32x4){0.f, 0.f, 0.f, 0.f};

    uint4 pa0 = *(const uint4*)GA0, pa1 = *(const uint4*)GA1;
    uint4 pb0 = *(const uint4*)GB0, pb1 = *(const uint4*)GB1;

    for (int k0 = 0; k0 < D_; k0 += 32) {
        __syncthreads();                 // prev tile's readers done
        *(uint4*)&As[r0][cg] = pa0;
        *(uint4*)&As[r1][cg] = pa1;
        *(uint4*)&Bs[r0][cg] = pb0;
        *(uint4*)&Bs[r1][cg] = pb1;
        __syncthreads();
        if (k0 + 32 < D_) {              // prefetch next tile (used next iter)
            pa0 = *(const uint4*)(GA0 + k0 + 32);
            pa1 = *(const uint4*)(GA1 + k0 + 32);
            pb0 = *(const uint4*)(GB0 + k0 + 32);
            pb1 = *(const uint4*)(GB1 + k0 + 32);
        }

        bf16x8 af[4], bf[4];
#pragma unroll
        for (int mt = 0; mt < 4; ++mt) af[mt] = *(const bf16x8*)&As[wm + mt * 16 + l15][quad * 8];
#pragma unroll
        for (int nt = 0; nt < 4; ++nt) bf[nt] = *(const bf16x8*)&Bs[wn + nt * 16 + l15][quad * 8];
#pragma unroll
        for (int mt = 0; mt < 4; ++mt)
#pragma unroll
            for (int nt = 0; nt < 4; ++nt)
                acc[mt][nt] = __builtin_amdgcn_mfma_f32_16x16x32_bf16(af[mt], bf[nt], acc[mt][nt], 0, 0, 0);
    }

    ushort* O = (z == 0) ? O0 : (z == 1) ? O1 : O2;
    // Q: fold 1/sqrt(64) AND log2e (exp2-domain softmax) into the scale
    const float scl = (z == 0) ? 0.18033688f : 1.0f;
#pragma unroll
    for (int mt = 0; mt < 4; ++mt)
#pragma unroll
        for (int nt = 0; nt < 4; ++nt) {
            if (z == 2) {
                // V transposed: Vt[bh][dd][n], 4 consecutive n per 8B store
                int rg0 = tileM + wm + mt * 16 + quad * 4;
                int cgc = tileN + wn + nt * 16 + l15;
                int b = rg0 >> 11, n0 = rg0 & (N_ - 1);
                int h = cgc >> 6, dd = cgc & 63;
                ushort4 o4;
                o4.x = f2b(acc[mt][nt][0]); o4.y = f2b(acc[mt][nt][1]);
                o4.z = f2b(acc[mt][nt][2]); o4.w = f2b(acc[mt][nt][3]);
                *(ushort4*)&O[((size_t)((b * H_ + h) * HD_ + dd)) * N_ + n0] = o4;
            } else {
#pragma unroll
                for (int r = 0; r < 4; ++r) {
                    int rg = tileM + wm + mt * 16 + quad * 4 + r;
                    int cgc = tileN + wn + nt * 16 + l15;
                    int b = rg >> 11, n = rg & (N_ - 1);
                    int h = cgc >> 6, dd = cgc & 63;
                    O[(((size_t)(b * H_ + h)) * N_ + n) * HD_ + dd] = f2b(acc[mt][nt][r] * scl);
                }
            }
        }
}

// ---------------------------------------------------------------------------
// Final GEMM (R7-verified bf16 form): out = AO @ Wo^T + bias, fp32 out.
// 128x64 tile (512 blocks = 2/CU). 4 waves 2x2, each 64x32.
// ---------------------------------------------------------------------------
__global__ __launch_bounds__(256)
void gemm_fin(const ushort* __restrict__ A, const ushort* __restrict__ W,
              const float* __restrict__ bias, float* __restrict__ Of)
{
    __shared__ alignas(16) ushort As[128][40];
    __shared__ alignas(16) ushort Bs[64][40];

    const int t = threadIdx.x;
    const int lane = t & 63, w = t >> 6;
    const int quad = lane >> 4, l15 = lane & 15;
    const int wm = (w >> 1) * 64, wn = (w & 1) * 32;
    const int tileM = blockIdx.x * 128, tileN = blockIdx.y * 64;

    const int r0 = t >> 2, r1 = 64 + (t >> 2);
    const int cg = (t & 3) * 8;
    const ushort* GA0 = A + (size_t)(tileM + r0) * D_ + cg;
    const ushort* GA1 = A + (size_t)(tileM + r1) * D_ + cg;
    const ushort* GB0 = W + (size_t)(tileN + r0) * D_ + cg;

    f32x4 acc[4][2];
#pragma unroll
    for (int mt = 0; mt < 4; ++mt)
#pragma unroll
        for (int nt = 0; nt < 2; ++nt) acc[mt][nt] = (f32x4){0.f, 0.f, 0.f, 0.f};

    uint4 pa0 = *(const uint4*)GA0, pa1 = *(const uint4*)GA1;
    uint4 pb0 = *(const uint4*)GB0;

    for (int k0 = 0; k0 < D_; k0 += 32) {
        __syncthreads();
        *(uint4*)&As[r0][cg] = pa0;
        *(uint4*)&As[r1][cg] = pa1;
        *(uint4*)&Bs[r0 & 63][cg] = pb0;
        __syncthreads();
        if (k0 + 32 < D_) {
            pa0 = *(const uint4*)(GA0 + k0 + 32);
            pa1 = *(const uint4*)(GA1 + k0 + 32);
            pb0 = *(const uint4*)(GB0 + k0 + 32);
        }

        bf16x8 af[4], bf[2];
#pragma unroll
        for (int mt = 0; mt < 4; ++mt) af[mt] = *(const bf16x8*)&As[wm + mt * 16 + l15][quad * 8];
#pragma unroll
        for (int nt = 0; nt < 2; ++nt) bf[nt] = *(const bf16x8*)&Bs[wn + nt * 16 + l15][quad * 8];
#pragma unroll
        for (int mt = 0; mt < 4; ++mt)
#pragma unroll
            for (int nt = 0; nt < 2; ++nt)
                acc[mt][nt] = __builtin_amdgcn_mfma_f32_16x16x32_bf16(af[mt], bf[nt], acc[mt][nt], 0, 0, 0);
    }

#pragma unroll
    for (int mt = 0; mt < 4; ++mt)
#pragma unroll
        for (int nt = 0; nt < 2; ++nt)
#pragma unroll
            for (int r = 0; r < 4; ++r) {
                int rg = tileM + wm + mt * 16 + quad * 4 + r;
                int cgc = tileN + wn + nt * 16 + l15;
                Of[(size_t)rg * D_ + cgc] = acc[mt][nt][r] + bias[cgc];
            }
}

// ---------------------------------------------------------------------------
// MFMA adaptive-temperature causal flash attention — FAT 128-KEY STAGES.
// R8 lesson: time = (serial chain per stage) x (stage count); TLP and VALU
// count are not binding. So halve the stage count in BOTH passes:
//   pass 1: Ks[128][72] holds 128 keys/stage            (33 -> ~17 stages)
//   pass 2: Ks[128][72] + Vs[64][136] (Vt for 128 keys); inner loop over two
//           64-key halves shares one barrier pair        (16.5 -> ~8.5 stages)
// Always stages 128 keys (base+128 <= 2048 by construction); mask predicates
// only in the final chunk (pass 1) / diag half (pass 2).
// LDS 45.3 KB -> 3 blocks/CU; grid 1024 queues 256 blocks, so qt-descending
// LPT ordering now actually schedules (bh = bid&31 keeps XCD L2 locality).
// exp2 domain (Q pre-scaled 0.125*log2e): Z = sum 2^(s2-C2),
// S2 = sum (s2-C2)2^(s2-C2), H = ln2*(log2 Z - S2/Z),
// w = exp2(fma(beta, s2, -beta*C2)).  Pass 2: O += w*V, Z' += w; O/Z'.
// ---------------------------------------------------------------------------
__global__ __launch_bounds__(256)
void attn_mfma(const ushort* __restrict__ Q, const ushort* __restrict__ K,
               const ushort* __restrict__ VT, ushort* __restrict__ AO)
{
    const int bid = blockIdx.x;
    const int qt = 31 - (bid >> 5);
    const int bh = bid & 31;
    const size_t kvbase = (size_t)bh * N_ * HD_;

    __shared__ alignas(16) ushort Ks[128][72];      // [key][hd], 128 keys/stage
    __shared__ alignas(16) ushort Vs[64][136];      // [hd][key], 128 keys + pad
    __shared__ alignas(16) ushort Ps[4][4][296];    // wave-private P, grp-padded

    const int t = threadIdx.x;
    const int lane = t & 63, w = t >> 6;
    const int quad = lane >> 4, l15 = lane & 15;
    const float SH2 = 11.5416913f;     // 8 * log2(e)
    const float LN2 = 0.69314718f;

    // K staging: thread covers rows skey+{0,32,64,96} of the 128-key chunk
    const int skey = t >> 3;            // 0..31
    const int skc  = (t & 7) * 8;       // 0..56
    const ushort* KS = K + kvbase + (size_t)skey * HD_ + skc;   // + key*HD_
    // V staging: thread covers hd rows vhd+{0,16,32,48}, key-cols vkc..vkc+7
    const int vhd = t >> 4;             // 0..15
    const int vkc = (t & 15) * 8;       // 0..120
    const ushort* VS = VT + kvbase + (size_t)vhd * N_ + vkc;    // + chunkbase

    const int qrow = w * 16 + quad * 4;
    const int qglob = qt * 64 + qrow;
    const int b = bh >> 4, h = bh & 15;
    const int nCh = (qt + 2) >> 1;      // 128-key chunks (last may be half-used)

    // Q fragments (registers all kernel)
    bf16x8 aq0, aq1;
    {
        const size_t qr = kvbase + (size_t)(qt * 64 + w * 16 + l15) * HD_;
        aq0 = *(const bf16x8*)&Q[qr + quad * 8];
        aq1 = *(const bf16x8*)&Q[qr + 32 + quad * 8];
    }

    float ez[4] = {0.f, 0.f, 0.f, 0.f};
    float sz[4] = {0.f, 0.f, 0.f, 0.f};

    // ---------------- pass 1: Z, S2 (128-key stages) ----------------
    uint4 k0 = *(const uint4*)KS;
    uint4 k1 = *(const uint4*)(KS + 32 * HD_);
    uint4 k2 = *(const uint4*)(KS + 64 * HD_);
    uint4 k3 = *(const uint4*)(KS + 96 * HD_);
    for (int c = 0; c < nCh; ++c) {
        __syncthreads();
        *(uint4*)&Ks[skey][skc]      = k0;
        *(uint4*)&Ks[32 + skey][skc] = k1;
        *(uint4*)&Ks[64 + skey][skc] = k2;
        *(uint4*)&Ks[96 + skey][skc] = k3;
        __syncthreads();
        if (c + 1 < nCh) {
            const ushort* nb = KS + (size_t)(c + 1) * (128 * HD_);
            k0 = *(const uint4*)nb;
            k1 = *(const uint4*)(nb + 32 * HD_);
            k2 = *(const uint4*)(nb + 64 * HD_);
            k3 = *(const uint4*)(nb + 96 * HD_);
        }
        if (c + 1 < nCh) {               // full chunk, unmasked, 8 tiles
#pragma unroll
            for (int nt = 0; nt < 8; ++nt) {
                f32x4 sv = (f32x4){0.f, 0.f, 0.f, 0.f};
                sv = __builtin_amdgcn_mfma_f32_16x16x32_bf16(aq0, *(const bf16x8*)&Ks[nt * 16 + l15][quad * 8], sv, 0, 0, 0);
                sv = __builtin_amdgcn_mfma_f32_16x16x32_bf16(aq1, *(const bf16x8*)&Ks[nt * 16 + l15][32 + quad * 8], sv, 0, 0, 0);
#pragma unroll
                for (int r = 0; r < 4; ++r) {
                    float sh = sv[r] - SH2;
                    float e = __builtin_amdgcn_exp2f(sh);
                    ez[r] += e;
                    sz[r] = fmaf(e, sh, sz[r]);
                }
            }
        } else {                         // last chunk: 4 or 8 tiles, predicated
            const int tiles = (((qt + 1) * 64) - c * 128) >> 4;
            const int kb0 = c * 128;
            for (int nt = 0; nt < tiles; ++nt) {
                f32x4 sv = (f32x4){0.f, 0.f, 0.f, 0.f};
                sv = __builtin_amdgcn_mfma_f32_16x16x32_bf16(aq0, *(const bf16x8*)&Ks[nt * 16 + l15][quad * 8], sv, 0, 0, 0);
                sv = __builtin_amdgcn_mfma_f32_16x16x32_bf16(aq1, *(const bf16x8*)&Ks[nt * 16 + l15][32 + quad * 8], sv, 0, 0, 0);
                const int kcol = kb0 + nt * 16 + l15;
#pragma unroll
                for (int r = 0; r < 4; ++r) {
                    float sh = sv[r] - SH2;
                    float e = (kcol <= qglob + r) ? __builtin_amdgcn_exp2f(sh) : 0.f;
                    ez[r] += e;
                    sz[r] = fmaf(e, sh, sz[r]);
                }
            }
        }
    }
    // hoisted 16-lane butterfly reduce
#pragma unroll
    for (int r = 0; r < 4; ++r) {
#pragma unroll
        for (int off = 1; off < 16; off <<= 1) {
            ez[r] += __shfl_xor(ez[r], off);
            sz[r] += __shfl_xor(sz[r], off);
        }
    }

    // ---------------- entropy -> beta ----------------
    float nbs[4], bl[4];   // w = exp2(fma(beta, s2, -beta*SH2))
#pragma unroll
    for (int r = 0; r < 4; ++r) {
        float Z = ez[r];
        float Hh = LN2 * (__builtin_amdgcn_logf(Z) - sz[r] / Z);
        float bb = 1.f;
        if (Hh > 0.5f) {
            float e2 = Hh * Hh;
            float pp = -0.037f * e2 * e2 + 0.481f * e2 * Hh - 2.3f * e2 + 4.917f * Hh - 1.791f;
            bb = fmaxf(pp, 1.f);
        }
        bl[r] = bb;
        nbs[r] = -bb * SH2;
    }

    // ---------------- pass 2: O, Z' (128-key stages, two 64-key halves) -----
    f32x4 ov[4];
#pragma unroll
    for (int nt = 0; nt < 4; ++nt) ov[nt] = (f32x4){0.f, 0.f, 0.f, 0.f};
    float zp[4] = {0.f, 0.f, 0.f, 0.f};

    k0 = *(const uint4*)KS;
    k1 = *(const uint4*)(KS + 32 * HD_);
    k2 = *(const uint4*)(KS + 64 * HD_);
    k3 = *(const uint4*)(KS + 96 * HD_);
    uint4 v0 = *(const uint4*)VS;
    uint4 v1 = *(const uint4*)(VS + 16 * N_);
    uint4 v2 = *(const uint4*)(VS + 32 * N_);
    uint4 v3 = *(const uint4*)(VS + 48 * N_);
    for (int c = 0; c < nCh; ++c) {
        __syncthreads();
        *(uint4*)&Ks[skey][skc]      = k0;
        *(uint4*)&Ks[32 + skey][skc] = k1;
        *(uint4*)&Ks[64 + skey][skc] = k2;
        *(uint4*)&Ks[96 + skey][skc] = k3;
        *(uint4*)&Vs[vhd][vkc]       = v0;
        *(uint4*)&Vs[16 + vhd][vkc]  = v1;
        *(uint4*)&Vs[32 + vhd][vkc]  = v2;
        *(uint4*)&Vs[48 + vhd][vkc]  = v3;
        __syncthreads();
        if (c + 1 < nCh) {
            const ushort* nk = KS + (size_t)(c + 1) * (128 * HD_);
            k0 = *(const uint4*)nk;
            k1 = *(const uint4*)(nk + 32 * HD_);
            k2 = *(const uint4*)(nk + 64 * HD_);
            k3 = *(const uint4*)(nk + 96 * HD_);
            const ushort* nv = VS + (c + 1) * 128;
            v0 = *(const uint4*)nv;
            v1 = *(const uint4*)(nv + 16 * N_);
            v2 = *(const uint4*)(nv + 32 * N_);
            v3 = *(const uint4*)(nv + 48 * N_);
        }
        const int halves = min(2, (qt + 1) - c * 2);
        for (int hh = 0; hh < halves; ++hh) {
            const bool diag = (c * 2 + hh == qt);

            float wv[4][4];
#pragma unroll
            for (int nt = 0; nt < 4; ++nt) {
                f32x4 sv = (f32x4){0.f, 0.f, 0.f, 0.f};
                sv = __builtin_amdgcn_mfma_f32_16x16x32_bf16(aq0, *(const bf16x8*)&Ks[hh * 64 + nt * 16 + l15][quad * 8], sv, 0, 0, 0);
                sv = __builtin_amdgcn_mfma_f32_16x16x32_bf16(aq1, *(const bf16x8*)&Ks[hh * 64 + nt * 16 + l15][32 + quad * 8], sv, 0, 0, 0);
                const int kcol = nt * 16 + l15;
#pragma unroll
                for (int r = 0; r < 4; ++r) {
                    float e = __builtin_amdgcn_exp2f(fmaf(bl[r], sv[r], nbs[r]));
                    wv[nt][r] = (!diag || (kcol <= qrow + r)) ? e : 0.f;
                }
            }
            // P -> wave-private LDS (C-layout write, A-layout read; same-wave)
#pragma unroll
            for (int nt = 0; nt < 4; ++nt)
#pragma unroll
                for (int r = 0; r < 4; ++r)
                    Ps[w][quad][r * 72 + nt * 16 + l15] = f2b_fast(wv[nt][r]);
#pragma unroll
            for (int r = 0; r < 4; ++r)
                zp[r] += (wv[0][r] + wv[1][r]) + (wv[2][r] + wv[3][r]);

            bf16x8 pa0 = *(const bf16x8*)&Ps[w][l15 >> 2][(l15 & 3) * 72 + quad * 8];
            bf16x8 pa1 = *(const bf16x8*)&Ps[w][l15 >> 2][(l15 & 3) * 72 + 32 + quad * 8];
#pragma unroll
            for (int nt = 0; nt < 4; ++nt) {
                ov[nt] = __builtin_amdgcn_mfma_f32_16x16x32_bf16(pa0, *(const bf16x8*)&Vs[nt * 16 + l15][hh * 64 + quad * 8], ov[nt], 0, 0, 0);
                ov[nt] = __builtin_amdgcn_mfma_f32_16x16x32_bf16(pa1, *(const bf16x8*)&Vs[nt * 16 + l15][hh * 64 + 32 + quad * 8], ov[nt], 0, 0, 0);
            }
        }
    }
    // hoisted Z' butterfly
#pragma unroll
    for (int r = 0; r < 4; ++r)
#pragma unroll
        for (int off = 1; off < 16; off <<= 1) zp[r] += __shfl_xor(zp[r], off);

    // ---------------- write AO [B, N, D] bf16 ----------------
#pragma unroll
    for (int r = 0; r < 4; ++r) {
        int qg = qt * 64 + w * 16 + quad * 4 + r;
        float inv = 1.f / zp[r];
        size_t rowoff = ((size_t)(b * N_ + qg)) * D_ + h * HD_;
#pragma unroll
        for (int nt = 0; nt < 4; ++nt)
            AO[rowoff + nt * 16 + l15] = f2b(ov[nt][r] * inv);
    }
}

// ---------------------------------------------------------------------------
extern "C" void kernel_launch(void* const* d_in, const int* in_sizes, int n_in,
                              void* d_out, int out_size, void* d_ws, size_t ws_size,
                              hipStream_t stream)
{
    const float* x  = (const float*)d_in[0];
    const float* Wq = (const float*)d_in[1];
    const float* Wk = (const float*)d_in[2];
    const float* Wv = (const float*)d_in[3];
    const float* Wo = (const float*)d_in[4];
    const float* bo = (const float*)d_in[5];
    float* out = (float*)d_out;

    ushort* ws  = (ushort*)d_ws;
    ushort* xb  = ws;                       // 4096*1024
    ushort* wqb = ws + 4194304;             // 1024*1024 each
    ushort* wkb = ws + 5242880;
    ushort* wvb = ws + 6291456;
    ushort* wob = ws + 7340032;
    ushort* Qb  = ws + 8388608;             // [32][2048][64]
    ushort* Kb  = ws + 12582912;            // [32][2048][64]
    ushort* Vtb = ws + 16777216;            // [32][64][2048]  (transposed V)
    ushort* aob = ws + 20971520;            // 4096*1024

    cvt_all<<<8192, 256, 0, stream>>>(x, Wq, Wk, Wv, Wo, xb);

    gemm_qkv<<<dim3(32, 8, 3), 256, 0, stream>>>(
        xb, wqb, wkb, wvb, Qb, Kb, Vtb);

    attn_mfma<<<dim3(1024), 256, 0, stream>>>(Qb, Kb, Vtb, aob);

    gemm_fin<<<dim3(32, 16), 256, 0, stream>>>(aob, wob, bo, out);
}